// Round 10
// baseline (796.572 us; speedup 1.0000x reference)
//
#include <hip/hip_runtime.h>
#include <math.h>

#define SLOPE 0.01f
#define BKS   1024       // dests per bucket
#define BSH2  10         // log2(BKS)
#define NBKMAX 512
#define CH    25600      // mlp node chunk (h1 chunk = 26.2 MB, overlays stage)

typedef short  bf16x8 __attribute__((ext_vector_type(8)));
typedef float  f32x4  __attribute__((ext_vector_type(4)));

__device__ __forceinline__ float lrelu(float v) { return v >= 0.f ? v : SLOPE * v; }

__device__ __forceinline__ unsigned short f2bf(float v) {
    unsigned u = __float_as_uint(v);
    return (unsigned short)((u + 0x7FFFu + ((u >> 16) & 1u)) >> 16);   // RNE
}
__device__ __forceinline__ float bf2f(unsigned short b) {
    return __uint_as_float(((unsigned)b) << 16);
}

// ---------------------------------------------------------------------------
// GRU step (h0=0) for both layers, regenerate GCN weights, fold Wout/bout.
// ---------------------------------------------------------------------------
__global__ void prep_k(const float* __restrict__ m1, const float* __restrict__ Wih1,
                       const float* __restrict__ bih1, const float* __restrict__ bhh1,
                       const float* __restrict__ m2, const float* __restrict__ Wih2,
                       const float* __restrict__ bih2, const float* __restrict__ bhh2,
                       const float* __restrict__ wtW1, const float* __restrict__ wtb1,
                       const float* __restrict__ wtW2, const float* __restrict__ wtb2,
                       const float* __restrict__ Wout, const float* __restrict__ bout,
                       float* __restrict__ Wn1, float* __restrict__ Wn2,
                       float* __restrict__ wsum, float* __restrict__ bsum) {
    __shared__ float nm[32];   // new_mem1 [0..15], new_mem2 [16..31]
    int t = threadIdx.x;
    if (t < 32) {
        int L = t >> 4, j = t & 15;
        const float* m   = L ? m2   : m1;
        const float* Wih = L ? Wih2 : Wih1;
        const float* bih = L ? bih2 : bih1;
        const float* bhh = L ? bhh2 : bhh1;
        float gr = bih[j], gz = bih[16 + j], gn = bih[32 + j];
        for (int k = 0; k < 16; ++k) {
            float mk = m[k];
            gr += Wih[j * 16 + k] * mk;
            gz += Wih[(16 + j) * 16 + k] * mk;
            gn += Wih[(32 + j) * 16 + k] * mk;
        }
        float r = 1.f / (1.f + expf(-(gr + bhh[j])));
        float z = 1.f / (1.f + expf(-(gz + bhh[16 + j])));
        float n = tanhf(gn + r * bhh[32 + j]);
        nm[t] = (1.f - z) * n;          // + z*h, h==0
    }
    __syncthreads();
    float s1 = wtb1[t], s2 = wtb2[t];
    for (int k = 0; k < 16; ++k) {
        s1 += wtW1[t * 16 + k] * nm[k];
        s2 += wtW2[t * 16 + k] * nm[16 + k];
    }
    Wn1[t] = s1;
    Wn2[t] = s2;
    if (t < 16) wsum[t] = Wout[t] + Wout[16 + t];
    if (t == 0) bsum[0] = bout[0] + bout[1];
}

// Split W1 into bf16 hi/lo pair (for split-bf16 MFMA GEMM). 32768 elems.
__global__ void wsplit_k(const float* __restrict__ W1,
                         unsigned short* __restrict__ W1h,
                         unsigned short* __restrict__ W1l) {
    int i = blockIdx.x * 256 + threadIdx.x;
    float v = W1[i];
    unsigned short h = f2bf(v);
    W1h[i] = h;
    W1l[i] = f2bf(v - bf2f(h));
}

// ---------------------------------------------------------------------------
// CSR build (no per-edge global atomics): bucket count -> scan -> scatter ->
// per-bucket LDS hist/scan/scatter.
// ---------------------------------------------------------------------------
__global__ void zb_k(int* __restrict__ btot) {
    btot[blockIdx.x * 256 + threadIdx.x] = 0;
}

__global__ void bcnt_k(const int* __restrict__ col, int* __restrict__ btot,
                       int E, int NBK) {
    __shared__ int lc[NBKMAX];
    int t = threadIdx.x;
    for (int i = t; i < NBK; i += 256) lc[i] = 0;
    __syncthreads();
    int base = blockIdx.x * 4096;
#pragma unroll
    for (int i = 0; i < 16; ++i) {
        int e = base + i * 256 + t;
        if (e < E) atomicAdd(&lc[col[e] >> BSH2], 1);
    }
    __syncthreads();
    for (int i = t; i < NBK; i += 256)
        if (lc[i]) atomicAdd(btot + i, lc[i]);
}

__global__ __launch_bounds__(512) void bscan_k(const int* __restrict__ btot,
                                               int* __restrict__ bbase,
                                               int* __restrict__ bfill,
                                               int* __restrict__ off,
                                               int NBK, int N, int E) {
    __shared__ int s[512];
    int t = threadIdx.x;
    int v = (t < NBK) ? btot[t] : 0;
    s[t] = v;
    __syncthreads();
    for (int d = 1; d < 512; d <<= 1) {
        int u = (t >= d) ? s[t - d] : 0;
        __syncthreads();
        s[t] += u;
        __syncthreads();
    }
    int ex = s[t] - v;
    if (t < NBK) { bbase[t] = ex; bfill[t] = ex; }
    if (t == 0) { bbase[NBK] = E; off[N] = E; }
}

__global__ void bscat_k(const int* __restrict__ row, const int* __restrict__ col,
                        int* __restrict__ bfill, int2* __restrict__ stage,
                        int E, int NBK) {
    __shared__ int lcnt[NBKMAX];
    __shared__ int lbase[NBKMAX];
    int t = threadIdx.x;
    for (int i = t; i < NBK; i += 256) lcnt[i] = 0;
    __syncthreads();
    int base = blockIdx.x * 4096;
    int r[16], d[16], sl[16];
#pragma unroll
    for (int i = 0; i < 16; ++i) {
        int e = base + i * 256 + t;
        if (e < E) {
            r[i]  = row[e];
            d[i]  = col[e];
            sl[i] = atomicAdd(&lcnt[d[i] >> BSH2], 1);
        } else d[i] = -1;
    }
    __syncthreads();
    for (int i = t; i < NBK; i += 256)
        lbase[i] = lcnt[i] ? atomicAdd(bfill + i, lcnt[i]) : 0;
    __syncthreads();
#pragma unroll
    for (int i = 0; i < 16; ++i) {
        if (d[i] >= 0)
            stage[lbase[d[i] >> BSH2] + sl[i]] = make_int2(r[i], d[i]);
    }
}

__global__ void bproc_k(const int2* __restrict__ stage, const int* __restrict__ bbase,
                        int* __restrict__ off, float* __restrict__ dis,
                        int* __restrict__ srcs, int N) {
    __shared__ int lh[BKS];
    __shared__ int lo[BKS];
    __shared__ int ssc[256];
    const int b = blockIdx.x;
    const int t = threadIdx.x;
    const int e0 = bbase[b], e1 = bbase[b + 1];
#pragma unroll
    for (int i = 0; i < 4; ++i) lh[t * 4 + i] = 0;
    __syncthreads();
    for (int e = e0 + t; e < e1; e += 256) {
        int2 v = stage[e];
        atomicAdd(&lh[v.y & (BKS - 1)], 1);
    }
    __syncthreads();
    int c0 = lh[t * 4], c1 = lh[t * 4 + 1], c2 = lh[t * 4 + 2], c3 = lh[t * 4 + 3];
    int tot = c0 + c1 + c2 + c3;
    ssc[t] = tot;
    __syncthreads();
    for (int d = 1; d < 256; d <<= 1) {
        int u = (t >= d) ? ssc[t - d] : 0;
        __syncthreads();
        ssc[t] += u;
        __syncthreads();
    }
    int ex = ssc[t] - tot;
    lo[t * 4]     = ex;
    lo[t * 4 + 1] = ex + c0;
    lo[t * 4 + 2] = ex + c0 + c1;
    lo[t * 4 + 3] = ex + c0 + c1 + c2;
    {
        int cs[4] = {c0, c1, c2, c3};
#pragma unroll
        for (int i = 0; i < 4; ++i) {
            int node = b * BKS + t * 4 + i;
            if (node < N) {
                off[node] = e0 + lo[t * 4 + i];
                dis[node] = rsqrtf((float)(cs[i] + 1));
            }
        }
    }
    __syncthreads();
#pragma unroll
    for (int i = 0; i < 4; ++i) lh[t * 4 + i] = lo[t * 4 + i];
    __syncthreads();
    for (int e = e0 + t; e < e1; e += 256) {
        int2 w = stage[e];
        int pos = e0 + atomicAdd(&lh[w.y & (BKS - 1)], 1);
        srcs[pos] = w.x;
    }
}

// ---------------------------------------------------------------------------
// mlp1: GEMM1 (chunk x 128 x 256) via split-bf16 MFMA -> h1 (fp32, global).
// A tiles in FRAGMENT-LINEAR LDS layout: tile(ks,mt) of 64 lanes x 16 B,
// read as ds_read_b128 at lane*16B (fully consecutive -> zero conflicts).
// 32 KB LDS, no stage2 in-kernel -> 4 blocks/CU (vs 2 for the fused v4).
// ---------------------------------------------------------------------------
__global__ __launch_bounds__(256, 4) void mlp1_k(
        const float* __restrict__ x,
        const unsigned short* __restrict__ W1h,
        const unsigned short* __restrict__ W1l,
        const float* __restrict__ b1,
        float* __restrict__ h1g, int n0, int N) {
    __shared__ unsigned short sh[16384];       // 32 KB: xh [0..8192), xlo [8192..)
    unsigned short* xh  = sh;
    unsigned short* xlo = sh + 8192;

    const int t      = threadIdx.x;
    const int nl     = t & 63;
    const int q      = __builtin_amdgcn_readfirstlane(t >> 6);
    const int lane15 = t & 15;
    const int quad   = (t & 63) >> 4;
    const int node   = n0 + blockIdx.x * 64 + nl;

    // ---- stage: fragment-linear. element (n,k) -> tile(k>>5, n>>4),
    //      slot ((k>>3)&3)*16 + (n&15), halfword j = k&7.
    //      thread (q,nl) owns k in [q*32, q*32+32): ks=q, quad_k=kk. ----
    {
        const int mt  = nl >> 4, l15 = nl & 15;
        if (node < N) {
            const float4* xr = (const float4*)(x + (size_t)node * 128) + q * 8;
#pragma unroll
            for (int kk = 0; kk < 4; ++kk) {
                float4 v0 = xr[kk * 2], v1 = xr[kk * 2 + 1];
                unsigned short h0 = f2bf(v0.x), h1_ = f2bf(v0.y), h2 = f2bf(v0.z), h3 = f2bf(v0.w);
                unsigned short h4 = f2bf(v1.x), h5 = f2bf(v1.y), h6 = f2bf(v1.z), h7 = f2bf(v1.w);
                uint4 hv = make_uint4((unsigned)h0 | ((unsigned)h1_ << 16),
                                      (unsigned)h2 | ((unsigned)h3 << 16),
                                      (unsigned)h4 | ((unsigned)h5 << 16),
                                      (unsigned)h6 | ((unsigned)h7 << 16));
                uint4 lv = make_uint4(
                    (unsigned)f2bf(v0.x - bf2f(h0)) | ((unsigned)f2bf(v0.y - bf2f(h1_)) << 16),
                    (unsigned)f2bf(v0.z - bf2f(h2)) | ((unsigned)f2bf(v0.w - bf2f(h3)) << 16),
                    (unsigned)f2bf(v1.x - bf2f(h4)) | ((unsigned)f2bf(v1.y - bf2f(h5)) << 16),
                    (unsigned)f2bf(v1.z - bf2f(h6)) | ((unsigned)f2bf(v1.w - bf2f(h7)) << 16));
                int dest = (q * 4 + mt) * 512 + (kk * 16 + l15) * 8;
                *(uint4*)&xh[dest]  = hv;
                *(uint4*)&xlo[dest] = lv;
            }
        } else {
#pragma unroll
            for (int kk = 0; kk < 4; ++kk) {
                int dest = (q * 4 + mt) * 512 + (kk * 16 + l15) * 8;
                *(uint4*)&xh[dest]  = make_uint4(0, 0, 0, 0);
                *(uint4*)&xlo[dest] = make_uint4(0, 0, 0, 0);
            }
        }
    }
    __syncthreads();

    // ---- GEMM1 ----
    f32x4 acc[4][4];
#pragma unroll
    for (int mt = 0; mt < 4; ++mt)
#pragma unroll
        for (int nt = 0; nt < 4; ++nt)
            acc[mt][nt] = (f32x4){0.f, 0.f, 0.f, 0.f};

#pragma unroll 1
    for (int ks = 0; ks < 4; ++ks) {
        bf16x8 ah[4], al[4];
        const int slot8 = (t & 63) * 8;
#pragma unroll
        for (int mt = 0; mt < 4; ++mt) {
            ah[mt] = *(const bf16x8*)(xh  + (ks * 4 + mt) * 512 + slot8);
            al[mt] = *(const bf16x8*)(xlo + (ks * 4 + mt) * 512 + slot8);
        }
        const int koff = ks * 32 + quad * 8;
#pragma unroll
        for (int nt = 0; nt < 4; ++nt) {
            size_t wo = (size_t)(q * 64 + nt * 16 + lane15) * 128 + koff;
            bf16x8 bh = *(const bf16x8*)(W1h + wo);
            bf16x8 bl = *(const bf16x8*)(W1l + wo);
#pragma unroll
            for (int mt = 0; mt < 4; ++mt) {
                acc[mt][nt] = __builtin_amdgcn_mfma_f32_16x16x32_bf16(ah[mt], bh, acc[mt][nt], 0, 0, 0);
                acc[mt][nt] = __builtin_amdgcn_mfma_f32_16x16x32_bf16(ah[mt], bl, acc[mt][nt], 0, 0, 0);
                acc[mt][nt] = __builtin_amdgcn_mfma_f32_16x16x32_bf16(al[mt], bh, acc[mt][nt], 0, 0, 0);
            }
        }
    }

    // ---- epilogue: h1g[local_row*256 + hu] = lrelu(acc + b1[hu]) ----
    const int lbase = blockIdx.x * 64;
#pragma unroll
    for (int nt = 0; nt < 4; ++nt) {
        int hu = q * 64 + nt * 16 + lane15;
        float bb = b1[hu];
#pragma unroll
        for (int mt = 0; mt < 4; ++mt) {
#pragma unroll
            for (int r = 0; r < 4; ++r) {
                int lrow = lbase + 16 * mt + quad * 4 + r;
                if (n0 + lrow < N)
                    h1g[(size_t)lrow * 256 + hu] = lrelu(acc[mt][nt][r] + bb);
            }
        }
    }
}

// ---------------------------------------------------------------------------
// mlp2: stream h1 chunk; 16 lanes per node (lane = channel c).
//   a2_c = h1[n] . W2[c] (W2 native [16][256]); h2 = lrelu(a2 + b2);
//   o_c = sum_j Wn1[c][j] shfl(h2, j); xl = dis * o.  HBM-bound, tiny state.
// ---------------------------------------------------------------------------
__global__ void mlp2_k(const float* __restrict__ h1g, const float* __restrict__ W2,
                       const float* __restrict__ b2, const float* __restrict__ Wn1,
                       const float* __restrict__ dis, float* __restrict__ xl,
                       int n0, int N, int nodes) {
    __shared__ float w[256];             // w[j*16+c] = Wn1[c*16+j]
    {
        int c = threadIdx.x & 15, j = threadIdx.x >> 4;
        w[threadIdx.x] = Wn1[c * 16 + j];
    }
    __syncthreads();
    int t = blockIdx.x * 256 + threadIdx.x;
    int n_loc = t >> 4;
    if (n_loc >= nodes) return;
    int c = t & 15;
    const float4* hp = (const float4*)(h1g + (size_t)n_loc * 256);
    const float4* wp = (const float4*)(W2 + c * 256);
    float s0 = 0.f, s1 = 0.f, s2 = 0.f, s3 = 0.f;
#pragma unroll 4
    for (int i = 0; i < 64; ++i) {
        float4 h = hp[i], wv = wp[i];
        s0 = fmaf(h.x, wv.x, s0);
        s1 = fmaf(h.y, wv.y, s1);
        s2 = fmaf(h.z, wv.z, s2);
        s3 = fmaf(h.w, wv.w, s3);
    }
    float h2 = lrelu(((s0 + s1) + (s2 + s3)) + b2[c]);
    float o = 0.f;
#pragma unroll
    for (int j = 0; j < 16; ++j) o = fmaf(w[j * 16 + c], __shfl(h2, j, 16), o);
    int node = n0 + n_loc;
    if (node < N) xl[(size_t)node * 16 + c] = dis[node] * o;
}

// ---------------------------------------------------------------------------
// Gather layer 1 (wave per node, 4 edges x 16 channels in flight)
// ---------------------------------------------------------------------------
__global__ void gather1_k(const int* __restrict__ off, const int* __restrict__ srcs,
                          const float* __restrict__ dis, const float* __restrict__ xin,
                          const float* __restrict__ bias, const float* __restrict__ Wn2,
                          float* __restrict__ xout, int N) {
    __shared__ float w[256];             // transposed: w[j*16+c] = Wn2[c*16+j]
    {
        int j = threadIdx.x >> 4, c = threadIdx.x & 15;
        w[threadIdx.x] = Wn2[c * 16 + j];
    }
    __syncthreads();
    int t = blockIdx.x * 256 + threadIdx.x;
    int n = t >> 6;
    if (n >= N) return;
    int lane = t & 63, sub = lane >> 4, c = lane & 15;
    float acc = (sub == 0) ? xin[(size_t)n * 16 + c] : 0.f;   // self term
    int e1 = off[n + 1];
    for (int e = off[n] + sub; e < e1; e += 4)
        acc += xin[(size_t)srcs[e] * 16 + c];
    acc += __shfl_xor(acc, 16);
    acc += __shfl_xor(acc, 32);
    float d = dis[n];
    float h = lrelu(fmaf(d, acc, bias[c]));
    float o = 0.f;
#pragma unroll
    for (int j = 0; j < 16; ++j) o = fmaf(w[j * 16 + c], __shfl(h, j, 16), o);
    if (sub == 0) xout[(size_t)n * 16 + c] = d * o;
}

// ---------------------------------------------------------------------------
// Gather layer 2 + final projection
// ---------------------------------------------------------------------------
__global__ void gather2_k(const int* __restrict__ off, const int* __restrict__ srcs,
                          const float* __restrict__ dis, const float* __restrict__ xin,
                          const float* __restrict__ bias, const float* __restrict__ wsum,
                          const float* __restrict__ bsum, float* __restrict__ out, int N) {
    int t = blockIdx.x * 256 + threadIdx.x;
    int n = t >> 6;
    if (n >= N) return;
    int lane = t & 63, sub = lane >> 4, c = lane & 15;
    float acc = (sub == 0) ? xin[(size_t)n * 16 + c] : 0.f;
    int e1 = off[n + 1];
    for (int e = off[n] + sub; e < e1; e += 4)
        acc += xin[(size_t)srcs[e] * 16 + c];
    acc += __shfl_xor(acc, 16);
    acc += __shfl_xor(acc, 32);
    float v = wsum[c] * lrelu(fmaf(dis[n], acc, bias[c]));
#pragma unroll
    for (int m = 1; m < 16; m <<= 1) v += __shfl_xor(v, m);
    if (lane == 0) out[n] = v + bsum[0];
}

// ---------------------------------------------------------------------------
extern "C" void kernel_launch(void* const* d_in, const int* in_sizes, int n_in,
                              void* d_out, int out_size, void* d_ws, size_t ws_size,
                              hipStream_t stream) {
    const float* x      = (const float*)d_in[0];
    const int*   edge   = (const int*)d_in[1];
    const float* W1     = (const float*)d_in[2];
    const float* b1     = (const float*)d_in[3];
    const float* W2     = (const float*)d_in[4];
    const float* b2     = (const float*)d_in[5];
    const float* mem1   = (const float*)d_in[6];
    const float* g1_Wih = (const float*)d_in[7];
    const float* g1_bih = (const float*)d_in[9];
    const float* g1_bhh = (const float*)d_in[10];
    const float* wt1_W  = (const float*)d_in[11];
    const float* wt1_b  = (const float*)d_in[12];
    const float* gcn1_b = (const float*)d_in[13];
    const float* mem2   = (const float*)d_in[14];
    const float* g2_Wih = (const float*)d_in[15];
    const float* g2_bih = (const float*)d_in[17];
    const float* g2_bhh = (const float*)d_in[18];
    const float* wt2_W  = (const float*)d_in[19];
    const float* wt2_b  = (const float*)d_in[20];
    const float* gcn2_b = (const float*)d_in[21];
    const float* Wout   = (const float*)d_in[22];
    const float* bout   = (const float*)d_in[23];
    float* out = (float*)d_out;

    const int N = in_sizes[0] / 128;
    const int E = in_sizes[1] / 2;
    const int* row = edge;
    const int* col = edge + E;

    const int NBK = (N + BKS - 1) >> BSH2;   // coarse buckets (98 @ N=100k)
    const int gG  = (N * 64 + 255) / 256;    // gather blocks (wave per node)
    const int gB  = (E + 4095) / 4096;       // bcnt/bscat blocks

    float* ws    = (float*)d_ws;
    float* bufA  = ws;                        // [N*16] xl1 (dis-scaled)
    float* bufB  = bufA + (size_t)N * 16;     // [N*16] xl2 (dis-scaled)
    float* dis   = bufB + (size_t)N * 16;     // [N]
    float* sm    = dis + N;                   // smalls
    float* Wn1   = sm;
    float* Wn2   = sm + 256;
    float* wsum  = sm + 512;
    float* bsum  = sm + 528;
    unsigned short* W1h = (unsigned short*)(sm + 544);    // [256*128] bf16 hi
    unsigned short* W1l = W1h + 32768;                    // [256*128] bf16 lo
    int*   btot  = (int*)(W1l + 32768);       // [512]
    int*   bbase = btot + 512;                // [513]
    int*   bfill = bbase + 513;               // [512]
    int*   off   = bfill + 512;               // [N+1]
    int*   srcs  = off + N + 1;               // [E]
    // stage: 16B-aligned int2[E]; reused after bproc_k as h1 chunk (CH*256 f32)
    size_t stoff = (size_t)(srcs + E - (int*)d_ws);
    stoff = (stoff + 3) & ~(size_t)3;
    int2*  stage = (int2*)((int*)d_ws + stoff);
    float* h1g   = (float*)stage;

    prep_k<<<1, 256, 0, stream>>>(mem1, g1_Wih, g1_bih, g1_bhh,
                                  mem2, g2_Wih, g2_bih, g2_bhh,
                                  wt1_W, wt1_b, wt2_W, wt2_b,
                                  Wout, bout, Wn1, Wn2, wsum, bsum);
    wsplit_k<<<128, 256, 0, stream>>>(W1, W1h, W1l);
    zb_k<<<2, 256, 0, stream>>>(btot);
    bcnt_k<<<gB, 256, 0, stream>>>(col, btot, E, NBK);
    bscan_k<<<1, 512, 0, stream>>>(btot, bbase, bfill, off, NBK, N, E);
    bscat_k<<<gB, 256, 0, stream>>>(row, col, bfill, stage, E, NBK);
    bproc_k<<<NBK, 256, 0, stream>>>(stage, bbase, off, dis, srcs, N);
    // MLP in chunks (h1 overlays the now-dead stage region)
    for (int n0 = 0; n0 < N; n0 += CH) {
        int nodes = (N - n0 < CH) ? (N - n0) : CH;
        int g1 = (nodes + 63) / 64;
        int g2 = (nodes + 15) / 16;
        mlp1_k<<<g1, 256, 0, stream>>>(x, W1h, W1l, b1, h1g, n0, N);
        mlp2_k<<<g2, 256, 0, stream>>>(h1g, W2, b2, Wn1, dis, bufA, n0, N, nodes);
    }
    gather1_k<<<gG, 256, 0, stream>>>(off, srcs, dis, bufA, gcn1_b, Wn2, bufB, N);
    gather2_k<<<gG, 256, 0, stream>>>(off, srcs, dis, bufB, gcn2_b, wsum, bsum, out, N);
}

// Round 11
// 480.243 us; speedup vs baseline: 1.6587x; 1.6587x over previous
//
#include <hip/hip_runtime.h>
#include <math.h>

#define SLOPE 0.01f
#define BKS   1024       // dests per bucket
#define BSH2  10         // log2(BKS)
#define NBKMAX 512

typedef short  bf16x8 __attribute__((ext_vector_type(8)));
typedef float  f32x4  __attribute__((ext_vector_type(4)));

__device__ __forceinline__ float lrelu(float v) { return v >= 0.f ? v : SLOPE * v; }

__device__ __forceinline__ unsigned short f2bf(float v) {
    unsigned u = __float_as_uint(v);
    return (unsigned short)((u + 0x7FFFu + ((u >> 16) & 1u)) >> 16);   // RNE
}
__device__ __forceinline__ float bf2f(unsigned short b) {
    return __uint_as_float(((unsigned)b) << 16);
}

// ---------------------------------------------------------------------------
// GRU step (h0=0) for both layers, regenerate GCN weights, fold Wout/bout,
// and transpose W2 -> W2t[hu][j] for contiguous stage-2 scalar loads.
// ---------------------------------------------------------------------------
__global__ void prep_k(const float* __restrict__ m1, const float* __restrict__ Wih1,
                       const float* __restrict__ bih1, const float* __restrict__ bhh1,
                       const float* __restrict__ m2, const float* __restrict__ Wih2,
                       const float* __restrict__ bih2, const float* __restrict__ bhh2,
                       const float* __restrict__ wtW1, const float* __restrict__ wtb1,
                       const float* __restrict__ wtW2, const float* __restrict__ wtb2,
                       const float* __restrict__ Wout, const float* __restrict__ bout,
                       const float* __restrict__ W2,
                       float* __restrict__ Wn1, float* __restrict__ Wn2,
                       float* __restrict__ wsum, float* __restrict__ bsum,
                       float* __restrict__ W2t) {
    __shared__ float nm[32];   // new_mem1 [0..15], new_mem2 [16..31]
    int t = threadIdx.x;
    if (t < 32) {
        int L = t >> 4, j = t & 15;
        const float* m   = L ? m2   : m1;
        const float* Wih = L ? Wih2 : Wih1;
        const float* bih = L ? bih2 : bih1;
        const float* bhh = L ? bhh2 : bhh1;
        float gr = bih[j], gz = bih[16 + j], gn = bih[32 + j];
        for (int k = 0; k < 16; ++k) {
            float mk = m[k];
            gr += Wih[j * 16 + k] * mk;
            gz += Wih[(16 + j) * 16 + k] * mk;
            gn += Wih[(32 + j) * 16 + k] * mk;
        }
        float r = 1.f / (1.f + expf(-(gr + bhh[j])));
        float z = 1.f / (1.f + expf(-(gz + bhh[16 + j])));
        float n = tanhf(gn + r * bhh[32 + j]);
        nm[t] = (1.f - z) * n;          // + z*h, h==0
    }
    __syncthreads();
    float s1 = wtb1[t], s2 = wtb2[t];
    for (int k = 0; k < 16; ++k) {
        s1 += wtW1[t * 16 + k] * nm[k];
        s2 += wtW2[t * 16 + k] * nm[16 + k];
    }
    Wn1[t] = s1;
    Wn2[t] = s2;
#pragma unroll
    for (int j = 0; j < 16; ++j) W2t[t * 16 + j] = W2[j * 256 + t];
    if (t < 16) wsum[t] = Wout[t] + Wout[16 + t];
    if (t == 0) bsum[0] = bout[0] + bout[1];
}

// Split W1 into bf16 hi/lo pair (for split-bf16 MFMA GEMM). 32768 elems.
__global__ void wsplit_k(const float* __restrict__ W1,
                         unsigned short* __restrict__ W1h,
                         unsigned short* __restrict__ W1l) {
    int i = blockIdx.x * 256 + threadIdx.x;
    float v = W1[i];
    unsigned short h = f2bf(v);
    W1h[i] = h;
    W1l[i] = f2bf(v - bf2f(h));
}

// ---------------------------------------------------------------------------
// CSR build (no per-edge global atomics): bucket count -> scan -> scatter ->
// per-bucket LDS hist/scan/scatter.
// ---------------------------------------------------------------------------
__global__ void zb_k(int* __restrict__ btot) {
    btot[blockIdx.x * 256 + threadIdx.x] = 0;
}

__global__ void bcnt_k(const int* __restrict__ col, int* __restrict__ btot,
                       int E, int NBK) {
    __shared__ int lc[NBKMAX];
    int t = threadIdx.x;
    for (int i = t; i < NBK; i += 256) lc[i] = 0;
    __syncthreads();
    int base = blockIdx.x * 4096;
#pragma unroll
    for (int i = 0; i < 16; ++i) {
        int e = base + i * 256 + t;
        if (e < E) atomicAdd(&lc[col[e] >> BSH2], 1);
    }
    __syncthreads();
    for (int i = t; i < NBK; i += 256)
        if (lc[i]) atomicAdd(btot + i, lc[i]);
}

__global__ __launch_bounds__(512) void bscan_k(const int* __restrict__ btot,
                                               int* __restrict__ bbase,
                                               int* __restrict__ bfill,
                                               int* __restrict__ off,
                                               int NBK, int N, int E) {
    __shared__ int s[512];
    int t = threadIdx.x;
    int v = (t < NBK) ? btot[t] : 0;
    s[t] = v;
    __syncthreads();
    for (int d = 1; d < 512; d <<= 1) {
        int u = (t >= d) ? s[t - d] : 0;
        __syncthreads();
        s[t] += u;
        __syncthreads();
    }
    int ex = s[t] - v;
    if (t < NBK) { bbase[t] = ex; bfill[t] = ex; }
    if (t == 0) { bbase[NBK] = E; off[N] = E; }
}

__global__ void bscat_k(const int* __restrict__ row, const int* __restrict__ col,
                        int* __restrict__ bfill, int2* __restrict__ stage,
                        int E, int NBK) {
    __shared__ int lcnt[NBKMAX];
    __shared__ int lbase[NBKMAX];
    int t = threadIdx.x;
    for (int i = t; i < NBK; i += 256) lcnt[i] = 0;
    __syncthreads();
    int base = blockIdx.x * 4096;
    int r[16], d[16], sl[16];
#pragma unroll
    for (int i = 0; i < 16; ++i) {
        int e = base + i * 256 + t;
        if (e < E) {
            r[i]  = row[e];
            d[i]  = col[e];
            sl[i] = atomicAdd(&lcnt[d[i] >> BSH2], 1);
        } else d[i] = -1;
    }
    __syncthreads();
    for (int i = t; i < NBK; i += 256)
        lbase[i] = lcnt[i] ? atomicAdd(bfill + i, lcnt[i]) : 0;
    __syncthreads();
#pragma unroll
    for (int i = 0; i < 16; ++i) {
        if (d[i] >= 0)
            stage[lbase[d[i] >> BSH2] + sl[i]] = make_int2(r[i], d[i]);
    }
}

__global__ void bproc_k(const int2* __restrict__ stage, const int* __restrict__ bbase,
                        int* __restrict__ off, float* __restrict__ dis,
                        int* __restrict__ srcs, int N) {
    __shared__ int lh[BKS];
    __shared__ int lo[BKS];
    __shared__ int ssc[256];
    const int b = blockIdx.x;
    const int t = threadIdx.x;
    const int e0 = bbase[b], e1 = bbase[b + 1];
#pragma unroll
    for (int i = 0; i < 4; ++i) lh[t * 4 + i] = 0;
    __syncthreads();
    for (int e = e0 + t; e < e1; e += 256) {
        int2 v = stage[e];
        atomicAdd(&lh[v.y & (BKS - 1)], 1);
    }
    __syncthreads();
    int c0 = lh[t * 4], c1 = lh[t * 4 + 1], c2 = lh[t * 4 + 2], c3 = lh[t * 4 + 3];
    int tot = c0 + c1 + c2 + c3;
    ssc[t] = tot;
    __syncthreads();
    for (int d = 1; d < 256; d <<= 1) {
        int u = (t >= d) ? ssc[t - d] : 0;
        __syncthreads();
        ssc[t] += u;
        __syncthreads();
    }
    int ex = ssc[t] - tot;
    lo[t * 4]     = ex;
    lo[t * 4 + 1] = ex + c0;
    lo[t * 4 + 2] = ex + c0 + c1;
    lo[t * 4 + 3] = ex + c0 + c1 + c2;
    {
        int cs[4] = {c0, c1, c2, c3};
#pragma unroll
        for (int i = 0; i < 4; ++i) {
            int node = b * BKS + t * 4 + i;
            if (node < N) {
                off[node] = e0 + lo[t * 4 + i];
                dis[node] = rsqrtf((float)(cs[i] + 1));
            }
        }
    }
    __syncthreads();
#pragma unroll
    for (int i = 0; i < 4; ++i) lh[t * 4 + i] = lo[t * 4 + i];
    __syncthreads();
    for (int e = e0 + t; e < e1; e += 256) {
        int2 w = stage[e];
        int pos = e0 + atomicAdd(&lh[w.y & (BKS - 1)], 1);
        srcs[pos] = w.x;
    }
}

// ---------------------------------------------------------------------------
// Fused MLP v4 (split-bf16 MFMA) — the R9-proven 96 µs version.
// ---------------------------------------------------------------------------
__global__ __launch_bounds__(256, 2) void mlp_k(
        const float* __restrict__ x,
        const unsigned short* __restrict__ W1h,
        const unsigned short* __restrict__ W1l,
        const float* __restrict__ b1, const float* __restrict__ W2t,
        const float* __restrict__ b2, const float* __restrict__ Wn1,
        const float* __restrict__ dis, float* __restrict__ xl, int N) {
    __shared__ float sbuf[17536];                    // 70144 B
    unsigned short* xh  = (unsigned short*)sbuf;     // [64][136] bf16 hi
    unsigned short* xlo = (unsigned short*)sbuf + 8704;  // [64][136] bf16 lo
    float* h1s = sbuf;                               // [64][257] fp32 (overlay)
    float* h2s = sbuf + 16448;                       // [64][17]

    const int t      = threadIdx.x;
    const int nl     = t & 63;
    const int q      = __builtin_amdgcn_readfirstlane(t >> 6);  // wave-uniform
    const int lane15 = t & 15;
    const int quad   = (t & 63) >> 4;
    const int node   = blockIdx.x * 64 + nl;

    // ---- stage x: load fp32 quarter-row, split to bf16 hi/lo in LDS ----
    {
        unsigned* xh32 = (unsigned*)xh;
        unsigned* xl32 = (unsigned*)xlo;
        int base = nl * 68 + q * 16;                 // uint index (row stride 68)
        if (node < N) {
            const float4* xr = (const float4*)(x + (size_t)node * 128) + q * 8;
#pragma unroll
            for (int kk = 0; kk < 8; ++kk) {
                float4 v = xr[kk];
                unsigned short hx = f2bf(v.x), hy = f2bf(v.y);
                unsigned short hz = f2bf(v.z), hw = f2bf(v.w);
                unsigned short lx = f2bf(v.x - bf2f(hx)), ly = f2bf(v.y - bf2f(hy));
                unsigned short lz = f2bf(v.z - bf2f(hz)), lw = f2bf(v.w - bf2f(hw));
                xh32[base + kk * 2]     = (unsigned)hx | ((unsigned)hy << 16);
                xh32[base + kk * 2 + 1] = (unsigned)hz | ((unsigned)hw << 16);
                xl32[base + kk * 2]     = (unsigned)lx | ((unsigned)ly << 16);
                xl32[base + kk * 2 + 1] = (unsigned)lz | ((unsigned)lw << 16);
            }
        } else {
#pragma unroll
            for (int kk = 0; kk < 8; ++kk) {
                xh32[base + kk * 2] = 0u; xh32[base + kk * 2 + 1] = 0u;
                xl32[base + kk * 2] = 0u; xl32[base + kk * 2 + 1] = 0u;
            }
        }
    }
    __syncthreads();

    // ---- GEMM1: wave q owns hu in [64q, 64q+64); 4 m-tiles x 4 n-tiles ----
    f32x4 acc[4][4];
#pragma unroll
    for (int mt = 0; mt < 4; ++mt)
#pragma unroll
        for (int nt = 0; nt < 4; ++nt)
            acc[mt][nt] = (f32x4){0.f, 0.f, 0.f, 0.f};

#pragma unroll 1
    for (int ks = 0; ks < 4; ++ks) {
        bf16x8 ah[4], al[4];
        const int koff = ks * 32 + quad * 8;
#pragma unroll
        for (int mt = 0; mt < 4; ++mt) {
            ah[mt] = *(const bf16x8*)(xh  + (16 * mt + lane15) * 136 + koff);
            al[mt] = *(const bf16x8*)(xlo + (16 * mt + lane15) * 136 + koff);
        }
#pragma unroll
        for (int nt = 0; nt < 4; ++nt) {
            size_t wo = (size_t)(q * 64 + nt * 16 + lane15) * 128 + koff;
            bf16x8 bh = *(const bf16x8*)(W1h + wo);
            bf16x8 bl = *(const bf16x8*)(W1l + wo);
#pragma unroll
            for (int mt = 0; mt < 4; ++mt) {
                acc[mt][nt] = __builtin_amdgcn_mfma_f32_16x16x32_bf16(ah[mt], bh, acc[mt][nt], 0, 0, 0);
                acc[mt][nt] = __builtin_amdgcn_mfma_f32_16x16x32_bf16(ah[mt], bl, acc[mt][nt], 0, 0, 0);
                acc[mt][nt] = __builtin_amdgcn_mfma_f32_16x16x32_bf16(al[mt], bh, acc[mt][nt], 0, 0, 0);
            }
        }
    }
    __syncthreads();   // x tile dead; safe to overlay h1s

    // ---- epilogue GEMM1: h1s[node_local][hu] = lrelu(acc + b1[hu]) ----
#pragma unroll
    for (int nt = 0; nt < 4; ++nt) {
        int hu = q * 64 + nt * 16 + lane15;
        float bb = b1[hu];
#pragma unroll
        for (int mt = 0; mt < 4; ++mt) {
            int rbase = (16 * mt + quad * 4) * 257 + hu;
#pragma unroll
            for (int r = 0; r < 4; ++r)
                h1s[rbase + r * 257] = lrelu(acc[mt][nt][r] + bb);
        }
    }
    __syncthreads();

    // ---- stage2: a2[j] = sum_hu h1s[nl][hu] * W2t[hu][j] ----
    {
        float a2[4] = {0.f, 0.f, 0.f, 0.f};
        const float* h1r = h1s + nl * 257;
        for (int hu = 0; hu < 256; hu += 4) {
#pragma unroll
            for (int u = 0; u < 4; ++u) {
                float h = h1r[hu + u];
                const float* wr = W2t + (hu + u) * 16 + q * 4;   // uniform -> s_load
                a2[0] = fmaf(h, wr[0], a2[0]);
                a2[1] = fmaf(h, wr[1], a2[1]);
                a2[2] = fmaf(h, wr[2], a2[2]);
                a2[3] = fmaf(h, wr[3], a2[3]);
            }
        }
#pragma unroll
        for (int jj = 0; jj < 4; ++jj) {
            int j = q * 4 + jj;
            h2s[nl * 17 + j] = lrelu(a2[jj] + b2[j]);
        }
    }
    __syncthreads();

    // ---- stage3: o = h2 @ Wn1^T, scaled by dis ----
    {
        const int c0 = q * 4;
        float o[4];
#pragma unroll
        for (int cc = 0; cc < 4; ++cc) {
            float s = 0.f;
#pragma unroll
            for (int j = 0; j < 16; ++j)
                s = fmaf(Wn1[(c0 + cc) * 16 + j], h2s[nl * 17 + j], s);
            o[cc] = s;
        }
        if (node < N) {
            float d = dis[node];
            float4* xo = (float4*)(xl + (size_t)node * 16 + c0);
            *xo = make_float4(d * o[0], d * o[1], d * o[2], d * o[3]);
        }
    }
}

// ---------------------------------------------------------------------------
// Gather layer 1 (wave per node, 4 edge-slots x 16 channels) with 4-deep
// batched gathers: 16 xin loads in flight per wave (R10 profile: gather was
// latency-bound -- VALUBusy 21%, 1 load in flight per lane).
// ---------------------------------------------------------------------------
__global__ void gather1_k(const int* __restrict__ off, const int* __restrict__ srcs,
                          const float* __restrict__ dis, const float* __restrict__ xin,
                          const float* __restrict__ bias, const float* __restrict__ Wn2,
                          float* __restrict__ xout, int N) {
    __shared__ float w[256];             // transposed: w[j*16+c] = Wn2[c*16+j]
    {
        int j = threadIdx.x >> 4, c = threadIdx.x & 15;
        w[threadIdx.x] = Wn2[c * 16 + j];
    }
    __syncthreads();
    int t = blockIdx.x * 256 + threadIdx.x;
    int n = t >> 6;
    if (n >= N) return;
    int lane = t & 63, sub = lane >> 4, c = lane & 15;
    float acc = (sub == 0) ? xin[(size_t)n * 16 + c] : 0.f;   // self term
    int e  = off[n] + sub;
    int e1 = off[n + 1];
    for (; e + 12 < e1; e += 16) {
        int s0 = srcs[e], s1 = srcs[e + 4], s2 = srcs[e + 8], s3 = srcs[e + 12];
        float v0 = xin[(size_t)s0 * 16 + c];
        float v1 = xin[(size_t)s1 * 16 + c];
        float v2 = xin[(size_t)s2 * 16 + c];
        float v3 = xin[(size_t)s3 * 16 + c];
        acc += (v0 + v1) + (v2 + v3);
    }
    for (; e < e1; e += 4)
        acc += xin[(size_t)srcs[e] * 16 + c];
    acc += __shfl_xor(acc, 16);
    acc += __shfl_xor(acc, 32);
    float d = dis[n];
    float h = lrelu(fmaf(d, acc, bias[c]));
    float o = 0.f;
#pragma unroll
    for (int j = 0; j < 16; ++j) o = fmaf(w[j * 16 + c], __shfl(h, j, 16), o);
    if (sub == 0) xout[(size_t)n * 16 + c] = d * o;
}

// ---------------------------------------------------------------------------
// Gather layer 2 + final projection (same 4-deep batching)
// ---------------------------------------------------------------------------
__global__ void gather2_k(const int* __restrict__ off, const int* __restrict__ srcs,
                          const float* __restrict__ dis, const float* __restrict__ xin,
                          const float* __restrict__ bias, const float* __restrict__ wsum,
                          const float* __restrict__ bsum, float* __restrict__ out, int N) {
    int t = blockIdx.x * 256 + threadIdx.x;
    int n = t >> 6;
    if (n >= N) return;
    int lane = t & 63, sub = lane >> 4, c = lane & 15;
    float acc = (sub == 0) ? xin[(size_t)n * 16 + c] : 0.f;
    int e  = off[n] + sub;
    int e1 = off[n + 1];
    for (; e + 12 < e1; e += 16) {
        int s0 = srcs[e], s1 = srcs[e + 4], s2 = srcs[e + 8], s3 = srcs[e + 12];
        float v0 = xin[(size_t)s0 * 16 + c];
        float v1 = xin[(size_t)s1 * 16 + c];
        float v2 = xin[(size_t)s2 * 16 + c];
        float v3 = xin[(size_t)s3 * 16 + c];
        acc += (v0 + v1) + (v2 + v3);
    }
    for (; e < e1; e += 4)
        acc += xin[(size_t)srcs[e] * 16 + c];
    acc += __shfl_xor(acc, 16);
    acc += __shfl_xor(acc, 32);
    float v = wsum[c] * lrelu(fmaf(dis[n], acc, bias[c]));
#pragma unroll
    for (int m = 1; m < 16; m <<= 1) v += __shfl_xor(v, m);
    if (lane == 0) out[n] = v + bsum[0];
}

// ---------------------------------------------------------------------------
extern "C" void kernel_launch(void* const* d_in, const int* in_sizes, int n_in,
                              void* d_out, int out_size, void* d_ws, size_t ws_size,
                              hipStream_t stream) {
    const float* x      = (const float*)d_in[0];
    const int*   edge   = (const int*)d_in[1];
    const float* W1     = (const float*)d_in[2];
    const float* b1     = (const float*)d_in[3];
    const float* W2     = (const float*)d_in[4];
    const float* b2     = (const float*)d_in[5];
    const float* mem1   = (const float*)d_in[6];
    const float* g1_Wih = (const float*)d_in[7];
    const float* g1_bih = (const float*)d_in[9];
    const float* g1_bhh = (const float*)d_in[10];
    const float* wt1_W  = (const float*)d_in[11];
    const float* wt1_b  = (const float*)d_in[12];
    const float* gcn1_b = (const float*)d_in[13];
    const float* mem2   = (const float*)d_in[14];
    const float* g2_Wih = (const float*)d_in[15];
    const float* g2_bih = (const float*)d_in[17];
    const float* g2_bhh = (const float*)d_in[18];
    const float* wt2_W  = (const float*)d_in[19];
    const float* wt2_b  = (const float*)d_in[20];
    const float* gcn2_b = (const float*)d_in[21];
    const float* Wout   = (const float*)d_in[22];
    const float* bout   = (const float*)d_in[23];
    float* out = (float*)d_out;

    const int N = in_sizes[0] / 128;
    const int E = in_sizes[1] / 2;
    const int* row = edge;
    const int* col = edge + E;

    const int NBK = (N + BKS - 1) >> BSH2;   // coarse buckets (98 @ N=100k)
    const int gM  = (N + 63) / 64;           // mlp blocks (64 nodes each)
    const int gG  = (N * 64 + 255) / 256;    // gather blocks (wave per node)
    const int gB  = (E + 4095) / 4096;       // bcnt/bscat blocks

    float* ws    = (float*)d_ws;
    float* bufA  = ws;                        // [N*16] xl1 (dis-scaled)
    float* bufB  = bufA + (size_t)N * 16;     // [N*16] xl2 (dis-scaled)
    float* dis   = bufB + (size_t)N * 16;     // [N]
    float* sm    = dis + N;                   // smalls
    float* Wn1   = sm;
    float* Wn2   = sm + 256;
    float* wsum  = sm + 512;
    float* bsum  = sm + 528;
    float* W2t   = sm + 544;                  // [256*16] transposed W2
    unsigned short* W1h = (unsigned short*)(sm + 4640);   // [256*128] bf16 hi
    unsigned short* W1l = (unsigned short*)(sm + 21024);  // [256*128] bf16 lo
    int*   btot  = (int*)(sm + 37408);        // [512]
    int*   bbase = btot + 512;                // [513]
    int*   bfill = bbase + 513;               // [512]
    int*   off   = bfill + 512;               // [N+1]
    int*   srcs  = off + N + 1;               // [E]
    // stage: 16B-aligned int2[E]
    size_t stoff = (size_t)(srcs + E - (int*)d_ws);
    stoff = (stoff + 3) & ~(size_t)3;
    int2*  stage = (int2*)((int*)d_ws + stoff);

    prep_k<<<1, 256, 0, stream>>>(mem1, g1_Wih, g1_bih, g1_bhh,
                                  mem2, g2_Wih, g2_bih, g2_bhh,
                                  wt1_W, wt1_b, wt2_W, wt2_b,
                                  Wout, bout, W2, Wn1, Wn2, wsum, bsum, W2t);
    wsplit_k<<<128, 256, 0, stream>>>(W1, W1h, W1l);
    zb_k<<<2, 256, 0, stream>>>(btot);
    bcnt_k<<<gB, 256, 0, stream>>>(col, btot, E, NBK);
    bscan_k<<<1, 512, 0, stream>>>(btot, bbase, bfill, off, NBK, N, E);
    bscat_k<<<gB, 256, 0, stream>>>(row, col, bfill, stage, E, NBK);
    bproc_k<<<NBK, 256, 0, stream>>>(stage, bbase, off, dis, srcs, N);
    mlp_k<<<gM, 256, 0, stream>>>(x, W1h, W1l, b1, W2t, b2, Wn1, dis, bufA, N);
    gather1_k<<<gG, 256, 0, stream>>>(off, srcs, dis, bufA, gcn1_b, Wn2, bufB, N);
    gather2_k<<<gG, 256, 0, stream>>>(off, srcs, dis, bufB, gcn2_b, wsum, bsum, out, N);
}

// Round 12
// 438.642 us; speedup vs baseline: 1.8160x; 1.0948x over previous
//
#include <hip/hip_runtime.h>
#include <math.h>

#define SLOPE 0.01f
#define BKS   1024       // dests per bucket
#define BSH2  10         // log2(BKS)
#define NBKMAX 128       // max coarse buckets (N <= 131072)
#define BCAP  36864      // fixed bucket capacity (mean 32.6k + 23 sigma)

typedef short  bf16x8 __attribute__((ext_vector_type(8)));
typedef float  f32x4  __attribute__((ext_vector_type(4)));

__device__ __forceinline__ float lrelu(float v) { return v >= 0.f ? v : SLOPE * v; }

__device__ __forceinline__ unsigned short f2bf(float v) {
    unsigned u = __float_as_uint(v);
    return (unsigned short)((u + 0x7FFFu + ((u >> 16) & 1u)) >> 16);   // RNE
}
__device__ __forceinline__ float bf2f(unsigned short b) {
    return __uint_as_float(((unsigned)b) << 16);
}

// ---------------------------------------------------------------------------
// GRU step (h0=0), regenerate GCN weights, fold Wout/bout, transpose W2,
// and init the fixed-capacity bucket cursors (bfill[b] = b*BCAP).
// ---------------------------------------------------------------------------
__global__ void prep_k(const float* __restrict__ m1, const float* __restrict__ Wih1,
                       const float* __restrict__ bih1, const float* __restrict__ bhh1,
                       const float* __restrict__ m2, const float* __restrict__ Wih2,
                       const float* __restrict__ bih2, const float* __restrict__ bhh2,
                       const float* __restrict__ wtW1, const float* __restrict__ wtb1,
                       const float* __restrict__ wtW2, const float* __restrict__ wtb2,
                       const float* __restrict__ Wout, const float* __restrict__ bout,
                       const float* __restrict__ W2,
                       float* __restrict__ Wn1, float* __restrict__ Wn2,
                       float* __restrict__ wsum, float* __restrict__ bsum,
                       float* __restrict__ W2t, int* __restrict__ bfill, int NBK) {
    __shared__ float nm[32];   // new_mem1 [0..15], new_mem2 [16..31]
    int t = threadIdx.x;
    if (t < 32) {
        int L = t >> 4, j = t & 15;
        const float* m   = L ? m2   : m1;
        const float* Wih = L ? Wih2 : Wih1;
        const float* bih = L ? bih2 : bih1;
        const float* bhh = L ? bhh2 : bhh1;
        float gr = bih[j], gz = bih[16 + j], gn = bih[32 + j];
        for (int k = 0; k < 16; ++k) {
            float mk = m[k];
            gr += Wih[j * 16 + k] * mk;
            gz += Wih[(16 + j) * 16 + k] * mk;
            gn += Wih[(32 + j) * 16 + k] * mk;
        }
        float r = 1.f / (1.f + expf(-(gr + bhh[j])));
        float z = 1.f / (1.f + expf(-(gz + bhh[16 + j])));
        float n = tanhf(gn + r * bhh[32 + j]);
        nm[t] = (1.f - z) * n;          // + z*h, h==0
    }
    __syncthreads();
    float s1 = wtb1[t], s2 = wtb2[t];
    for (int k = 0; k < 16; ++k) {
        s1 += wtW1[t * 16 + k] * nm[k];
        s2 += wtW2[t * 16 + k] * nm[16 + k];
    }
    Wn1[t] = s1;
    Wn2[t] = s2;
#pragma unroll
    for (int j = 0; j < 16; ++j) W2t[t * 16 + j] = W2[j * 256 + t];
    if (t < 16) wsum[t] = Wout[t] + Wout[16 + t];
    if (t == 0) bsum[0] = bout[0] + bout[1];
    if (t < NBK) bfill[t] = t * BCAP;
}

// Split W1 into bf16 hi/lo pair (for split-bf16 MFMA GEMM). 32768 elems.
__global__ void wsplit_k(const float* __restrict__ W1,
                         unsigned short* __restrict__ W1h,
                         unsigned short* __restrict__ W1l) {
    int i = blockIdx.x * 256 + threadIdx.x;
    float v = W1[i];
    unsigned short h = f2bf(v);
    W1h[i] = h;
    W1l[i] = f2bf(v - bf2f(h));
}

// ---------------------------------------------------------------------------
// CSR build v4: bscat (fixed-base buckets) -> cscan (1 block) -> bproc.
// ---------------------------------------------------------------------------
__global__ void bscat_k(const int* __restrict__ row, const int* __restrict__ col,
                        int* __restrict__ bfill, int2* __restrict__ stage,
                        int E, int NBK) {
    __shared__ int lcnt[NBKMAX];
    __shared__ int lbase[NBKMAX];
    int t = threadIdx.x;
    if (t < NBK) lcnt[t] = 0;
    __syncthreads();
    int base = blockIdx.x * 4096;
    int r[16], d[16], sl[16];
#pragma unroll
    for (int i = 0; i < 16; ++i) {
        int e = base + i * 256 + t;
        if (e < E) {
            r[i]  = row[e];
            d[i]  = col[e];
            sl[i] = atomicAdd(&lcnt[d[i] >> BSH2], 1);
        } else d[i] = -1;
    }
    __syncthreads();
    if (t < NBK) lbase[t] = lcnt[t] ? atomicAdd(bfill + t, lcnt[t]) : 0;
    __syncthreads();
#pragma unroll
    for (int i = 0; i < 16; ++i) {
        if (d[i] >= 0)
            stage[lbase[d[i] >> BSH2] + sl[i]] = make_int2(r[i], d[i]);
    }
}

// single block: counts from bfill, exclusive scan -> contiguous CSR bases
__global__ __launch_bounds__(128) void cscan_k(const int* __restrict__ bfill,
                                               int* __restrict__ bbase2,
                                               int* __restrict__ off,
                                               int NBK, int N, int E) {
    __shared__ int s[128];
    int t = threadIdx.x;
    int v = (t < NBK) ? (bfill[t] - t * BCAP) : 0;
    s[t] = v;
    __syncthreads();
    for (int d = 1; d < 128; d <<= 1) {
        int u = (t >= d) ? s[t - d] : 0;
        __syncthreads();
        s[t] += u;
        __syncthreads();
    }
    if (t < NBK) bbase2[t] = s[t] - v;
    if (t == 0) { bbase2[NBK] = E; off[N] = E; }
}

// one block per bucket: LDS hist -> LDS scan -> off/dis -> in-window scatter
__global__ void bproc_k(const int2* __restrict__ stage, const int* __restrict__ bbase2,
                        int* __restrict__ off, float* __restrict__ dis,
                        int* __restrict__ srcs, int N) {
    __shared__ int lh[BKS];
    __shared__ int lo[BKS];
    __shared__ int ssc[256];
    const int b  = blockIdx.x;
    const int t  = threadIdx.x;
    const int sb = b * BCAP;                     // stage read base
    const int e0 = bbase2[b];
    const int cnt = bbase2[b + 1] - e0;
#pragma unroll
    for (int i = 0; i < 4; ++i) lh[t * 4 + i] = 0;
    __syncthreads();
    for (int i = t; i < cnt; i += 256) {
        int2 v = stage[sb + i];
        atomicAdd(&lh[v.y & (BKS - 1)], 1);
    }
    __syncthreads();
    int c0 = lh[t * 4], c1 = lh[t * 4 + 1], c2 = lh[t * 4 + 2], c3 = lh[t * 4 + 3];
    int tot = c0 + c1 + c2 + c3;
    ssc[t] = tot;
    __syncthreads();
    for (int d = 1; d < 256; d <<= 1) {
        int u = (t >= d) ? ssc[t - d] : 0;
        __syncthreads();
        ssc[t] += u;
        __syncthreads();
    }
    int ex = ssc[t] - tot;
    lo[t * 4]     = ex;
    lo[t * 4 + 1] = ex + c0;
    lo[t * 4 + 2] = ex + c0 + c1;
    lo[t * 4 + 3] = ex + c0 + c1 + c2;
    {
        int cs[4] = {c0, c1, c2, c3};
#pragma unroll
        for (int i = 0; i < 4; ++i) {
            int node = b * BKS + t * 4 + i;
            if (node < N) {
                off[node] = e0 + lo[t * 4 + i];
                dis[node] = rsqrtf((float)(cs[i] + 1));   // in-degree + self-loop
            }
        }
    }
    __syncthreads();
#pragma unroll
    for (int i = 0; i < 4; ++i) lh[t * 4 + i] = lo[t * 4 + i];
    __syncthreads();
    for (int i = t; i < cnt; i += 256) {
        int2 w = stage[sb + i];
        int pos = e0 + atomicAdd(&lh[w.y & (BKS - 1)], 1);
        srcs[pos] = w.x;
    }
}

// ---------------------------------------------------------------------------
// Fused MLP v5 (split-bf16 MFMA, 8 waves / 512 threads per 64-node block):
// same 70 KB LDS, but 16 waves/CU (4/SIMD) instead of 8 — doubles latency
// hiding (R11: 75% stall at 2 waves/SIMD). Wave q owns hu [q*32, q*32+32).
// ---------------------------------------------------------------------------
__global__ __launch_bounds__(512, 4) void mlp_k(
        const float* __restrict__ x,
        const unsigned short* __restrict__ W1h,
        const unsigned short* __restrict__ W1l,
        const float* __restrict__ b1, const float* __restrict__ W2t,
        const float* __restrict__ b2, const float* __restrict__ Wn1,
        const float* __restrict__ dis, float* __restrict__ xl, int N) {
    __shared__ float sbuf[17536];                    // 70144 B
    unsigned short* xh  = (unsigned short*)sbuf;     // [64][136] bf16 hi
    unsigned short* xlo = (unsigned short*)sbuf + 8704;  // [64][136] bf16 lo
    float* h1s = sbuf;                               // [64][257] fp32 (overlay)
    float* h2s = sbuf + 16448;                       // [64][17]

    const int t      = threadIdx.x;
    const int nl     = t & 63;
    const int q      = __builtin_amdgcn_readfirstlane(t >> 6);  // wave 0..7
    const int lane15 = t & 15;
    const int quad   = (t & 63) >> 4;
    const int node   = blockIdx.x * 64 + nl;

    // ---- stage x: wave q stages k in [q*16, q*16+16) for its node ----
    {
        unsigned* xh32 = (unsigned*)xh;
        unsigned* xl32 = (unsigned*)xlo;
        int base = nl * 68 + q * 8;                  // uint index (row stride 68)
        if (node < N) {
            const float4* xr = (const float4*)(x + (size_t)node * 128) + q * 4;
#pragma unroll
            for (int kk = 0; kk < 4; ++kk) {
                float4 v = xr[kk];
                unsigned short hx = f2bf(v.x), hy = f2bf(v.y);
                unsigned short hz = f2bf(v.z), hw = f2bf(v.w);
                unsigned short lx = f2bf(v.x - bf2f(hx)), ly = f2bf(v.y - bf2f(hy));
                unsigned short lz = f2bf(v.z - bf2f(hz)), lw = f2bf(v.w - bf2f(hw));
                xh32[base + kk * 2]     = (unsigned)hx | ((unsigned)hy << 16);
                xh32[base + kk * 2 + 1] = (unsigned)hz | ((unsigned)hw << 16);
                xl32[base + kk * 2]     = (unsigned)lx | ((unsigned)ly << 16);
                xl32[base + kk * 2 + 1] = (unsigned)lz | ((unsigned)lw << 16);
            }
        } else {
#pragma unroll
            for (int kk = 0; kk < 4; ++kk) {
                xh32[base + kk * 2] = 0u; xh32[base + kk * 2 + 1] = 0u;
                xl32[base + kk * 2] = 0u; xl32[base + kk * 2 + 1] = 0u;
            }
        }
    }
    __syncthreads();

    // ---- GEMM1: wave q owns hu in [q*32, q*32+32); 4 m-tiles x 2 n-tiles ----
    f32x4 acc[4][2];
#pragma unroll
    for (int mt = 0; mt < 4; ++mt)
#pragma unroll
        for (int nt = 0; nt < 2; ++nt)
            acc[mt][nt] = (f32x4){0.f, 0.f, 0.f, 0.f};

#pragma unroll 1
    for (int ks = 0; ks < 4; ++ks) {
        bf16x8 ah[4], al[4];
        const int koff = ks * 32 + quad * 8;
#pragma unroll
        for (int mt = 0; mt < 4; ++mt) {
            ah[mt] = *(const bf16x8*)(xh  + (16 * mt + lane15) * 136 + koff);
            al[mt] = *(const bf16x8*)(xlo + (16 * mt + lane15) * 136 + koff);
        }
#pragma unroll
        for (int nt = 0; nt < 2; ++nt) {
            size_t wo = (size_t)(q * 32 + nt * 16 + lane15) * 128 + koff;
            bf16x8 bh = *(const bf16x8*)(W1h + wo);
            bf16x8 bl = *(const bf16x8*)(W1l + wo);
#pragma unroll
            for (int mt = 0; mt < 4; ++mt) {
                acc[mt][nt] = __builtin_amdgcn_mfma_f32_16x16x32_bf16(ah[mt], bh, acc[mt][nt], 0, 0, 0);
                acc[mt][nt] = __builtin_amdgcn_mfma_f32_16x16x32_bf16(ah[mt], bl, acc[mt][nt], 0, 0, 0);
                acc[mt][nt] = __builtin_amdgcn_mfma_f32_16x16x32_bf16(al[mt], bh, acc[mt][nt], 0, 0, 0);
            }
        }
    }
    __syncthreads();   // x tile dead; safe to overlay h1s

    // ---- epilogue GEMM1: h1s[row][hu] = lrelu(acc + b1[hu]) ----
#pragma unroll
    for (int nt = 0; nt < 2; ++nt) {
        int hu = q * 32 + nt * 16 + lane15;
        float bb = b1[hu];
#pragma unroll
        for (int mt = 0; mt < 4; ++mt) {
            int rbase = (16 * mt + quad * 4) * 257 + hu;
#pragma unroll
            for (int r = 0; r < 4; ++r)
                h1s[rbase + r * 257] = lrelu(acc[mt][nt][r] + bb);
        }
    }
    __syncthreads();

    // ---- stage2: wave q computes j in {2q, 2q+1} for its node nl ----
    {
        float a2[2] = {0.f, 0.f};
        const float* h1r = h1s + nl * 257;
        for (int hu = 0; hu < 256; hu += 4) {
#pragma unroll
            for (int u = 0; u < 4; ++u) {
                float h = h1r[hu + u];
                const float* wr = W2t + (hu + u) * 16 + q * 2;   // uniform -> s_load
                a2[0] = fmaf(h, wr[0], a2[0]);
                a2[1] = fmaf(h, wr[1], a2[1]);
            }
        }
#pragma unroll
        for (int jj = 0; jj < 2; ++jj) {
            int j = q * 2 + jj;
            h2s[nl * 17 + j] = lrelu(a2[jj] + b2[j]);
        }
    }
    __syncthreads();

    // ---- stage3 (waves 0..3): o = h2 @ Wn1^T, scaled by dis ----
    if (q < 4) {
        const int c0 = q * 4;
        float o[4];
#pragma unroll
        for (int cc = 0; cc < 4; ++cc) {
            float s = 0.f;
#pragma unroll
            for (int j = 0; j < 16; ++j)
                s = fmaf(Wn1[(c0 + cc) * 16 + j], h2s[nl * 17 + j], s);
            o[cc] = s;
        }
        if (node < N) {
            float d = dis[node];
            float4* xo = (float4*)(xl + (size_t)node * 16 + c0);
            *xo = make_float4(d * o[0], d * o[1], d * o[2], d * o[3]);
        }
    }
}

// ---------------------------------------------------------------------------
// Gather layer 1 (wave per node, 4-deep batched gathers — R11-proven)
// ---------------------------------------------------------------------------
__global__ void gather1_k(const int* __restrict__ off, const int* __restrict__ srcs,
                          const float* __restrict__ dis, const float* __restrict__ xin,
                          const float* __restrict__ bias, const float* __restrict__ Wn2,
                          float* __restrict__ xout, int N) {
    __shared__ float w[256];             // transposed: w[j*16+c] = Wn2[c*16+j]
    {
        int j = threadIdx.x >> 4, c = threadIdx.x & 15;
        w[threadIdx.x] = Wn2[c * 16 + j];
    }
    __syncthreads();
    int t = blockIdx.x * 256 + threadIdx.x;
    int n = t >> 6;
    if (n >= N) return;
    int lane = t & 63, sub = lane >> 4, c = lane & 15;
    float acc = (sub == 0) ? xin[(size_t)n * 16 + c] : 0.f;   // self term
    int e  = off[n] + sub;
    int e1 = off[n + 1];
    for (; e + 12 < e1; e += 16) {
        int s0 = srcs[e], s1 = srcs[e + 4], s2 = srcs[e + 8], s3 = srcs[e + 12];
        float v0 = xin[(size_t)s0 * 16 + c];
        float v1 = xin[(size_t)s1 * 16 + c];
        float v2 = xin[(size_t)s2 * 16 + c];
        float v3 = xin[(size_t)s3 * 16 + c];
        acc += (v0 + v1) + (v2 + v3);
    }
    for (; e < e1; e += 4)
        acc += xin[(size_t)srcs[e] * 16 + c];
    acc += __shfl_xor(acc, 16);
    acc += __shfl_xor(acc, 32);
    float d = dis[n];
    float h = lrelu(fmaf(d, acc, bias[c]));
    float o = 0.f;
#pragma unroll
    for (int j = 0; j < 16; ++j) o = fmaf(w[j * 16 + c], __shfl(h, j, 16), o);
    if (sub == 0) xout[(size_t)n * 16 + c] = d * o;
}

// ---------------------------------------------------------------------------
// Gather layer 2 + final projection (same 4-deep batching)
// ---------------------------------------------------------------------------
__global__ void gather2_k(const int* __restrict__ off, const int* __restrict__ srcs,
                          const float* __restrict__ dis, const float* __restrict__ xin,
                          const float* __restrict__ bias, const float* __restrict__ wsum,
                          const float* __restrict__ bsum, float* __restrict__ out, int N) {
    int t = blockIdx.x * 256 + threadIdx.x;
    int n = t >> 6;
    if (n >= N) return;
    int lane = t & 63, sub = lane >> 4, c = lane & 15;
    float acc = (sub == 0) ? xin[(size_t)n * 16 + c] : 0.f;
    int e  = off[n] + sub;
    int e1 = off[n + 1];
    for (; e + 12 < e1; e += 16) {
        int s0 = srcs[e], s1 = srcs[e + 4], s2 = srcs[e + 8], s3 = srcs[e + 12];
        float v0 = xin[(size_t)s0 * 16 + c];
        float v1 = xin[(size_t)s1 * 16 + c];
        float v2 = xin[(size_t)s2 * 16 + c];
        float v3 = xin[(size_t)s3 * 16 + c];
        acc += (v0 + v1) + (v2 + v3);
    }
    for (; e < e1; e += 4)
        acc += xin[(size_t)srcs[e] * 16 + c];
    acc += __shfl_xor(acc, 16);
    acc += __shfl_xor(acc, 32);
    float v = wsum[c] * lrelu(fmaf(dis[n], acc, bias[c]));
#pragma unroll
    for (int m = 1; m < 16; m <<= 1) v += __shfl_xor(v, m);
    if (lane == 0) out[n] = v + bsum[0];
}

// ---------------------------------------------------------------------------
extern "C" void kernel_launch(void* const* d_in, const int* in_sizes, int n_in,
                              void* d_out, int out_size, void* d_ws, size_t ws_size,
                              hipStream_t stream) {
    const float* x      = (const float*)d_in[0];
    const int*   edge   = (const int*)d_in[1];
    const float* W1     = (const float*)d_in[2];
    const float* b1     = (const float*)d_in[3];
    const float* W2     = (const float*)d_in[4];
    const float* b2     = (const float*)d_in[5];
    const float* mem1   = (const float*)d_in[6];
    const float* g1_Wih = (const float*)d_in[7];
    const float* g1_bih = (const float*)d_in[9];
    const float* g1_bhh = (const float*)d_in[10];
    const float* wt1_W  = (const float*)d_in[11];
    const float* wt1_b  = (const float*)d_in[12];
    const float* gcn1_b = (const float*)d_in[13];
    const float* mem2   = (const float*)d_in[14];
    const float* g2_Wih = (const float*)d_in[15];
    const float* g2_bih = (const float*)d_in[17];
    const float* g2_bhh = (const float*)d_in[18];
    const float* wt2_W  = (const float*)d_in[19];
    const float* wt2_b  = (const float*)d_in[20];
    const float* gcn2_b = (const float*)d_in[21];
    const float* Wout   = (const float*)d_in[22];
    const float* bout   = (const float*)d_in[23];
    float* out = (float*)d_out;

    const int N = in_sizes[0] / 128;
    const int E = in_sizes[1] / 2;
    const int* row = edge;
    const int* col = edge + E;

    const int NBK = (N + BKS - 1) >> BSH2;   // coarse buckets (98 @ N=100k)
    const int gM  = (N + 63) / 64;           // mlp blocks (64 nodes, 512 thr)
    const int gG  = (N * 64 + 255) / 256;    // gather blocks (wave per node)
    const int gB  = (E + 4095) / 4096;       // bscat blocks

    float* ws    = (float*)d_ws;
    float* bufA  = ws;                        // [N*16] xl1 (dis-scaled)
    float* bufB  = bufA + (size_t)N * 16;     // [N*16] xl2 (dis-scaled)
    float* dis   = bufB + (size_t)N * 16;     // [N]
    float* sm    = dis + N;                   // smalls
    float* Wn1   = sm;
    float* Wn2   = sm + 256;
    float* wsum  = sm + 512;
    float* bsum  = sm + 528;
    float* W2t   = sm + 544;                  // [256*16] transposed W2
    unsigned short* W1h = (unsigned short*)(sm + 4640);   // [256*128] bf16 hi
    unsigned short* W1l = (unsigned short*)(sm + 21024);  // [256*128] bf16 lo
    int*   bfill = (int*)(sm + 37408);        // [NBKMAX]
    int*   bbase2= bfill + NBKMAX;            // [NBKMAX+1]
    int*   off   = bbase2 + NBKMAX + 1;       // [N+1]
    int*   srcs  = off + N + 1;               // [E]
    // stage: 16B-aligned int2[NBK*BCAP]
    size_t stoff = (size_t)(srcs + E - (int*)d_ws);
    stoff = (stoff + 3) & ~(size_t)3;
    int2*  stage = (int2*)((int*)d_ws + stoff);

    prep_k<<<1, 256, 0, stream>>>(mem1, g1_Wih, g1_bih, g1_bhh,
                                  mem2, g2_Wih, g2_bih, g2_bhh,
                                  wt1_W, wt1_b, wt2_W, wt2_b,
                                  Wout, bout, W2, Wn1, Wn2, wsum, bsum,
                                  W2t, bfill, NBK);
    wsplit_k<<<128, 256, 0, stream>>>(W1, W1h, W1l);
    bscat_k<<<gB, 256, 0, stream>>>(row, col, bfill, stage, E, NBK);
    cscan_k<<<1, 128, 0, stream>>>(bfill, bbase2, off, NBK, N, E);
    bproc_k<<<NBK, 256, 0, stream>>>(stage, bbase2, off, dis, srcs, N);
    mlp_k<<<gM, 512, 0, stream>>>(x, W1h, W1l, b1, W2t, b2, Wn1, dis, bufA, N);
    gather1_k<<<gG, 256, 0, stream>>>(off, srcs, dis, bufA, gcn1_b, Wn2, bufB, N);
    gather2_k<<<gG, 256, 0, stream>>>(off, srcs, dis, bufB, gcn2_b, wsum, bsum, out, N);
}

// Round 13
// 400.559 us; speedup vs baseline: 1.9887x; 1.0951x over previous
//
#include <hip/hip_runtime.h>
#include <math.h>

#define SLOPE 0.01f
#define BKS   256        // dests per bucket (R12: 1024 -> 98 blocks was launch-width-bound)
#define BSH2  8          // log2(BKS)
#define NBKMAX 512       // max coarse buckets (N <= 131072)
#define BCAP  10240      // fixed bucket capacity (mean 8192 + 22 sigma)

typedef short  bf16x8 __attribute__((ext_vector_type(8)));
typedef float  f32x4  __attribute__((ext_vector_type(4)));

__device__ __forceinline__ float lrelu(float v) { return v >= 0.f ? v : SLOPE * v; }

__device__ __forceinline__ unsigned short f2bf(float v) {
    unsigned u = __float_as_uint(v);
    return (unsigned short)((u + 0x7FFFu + ((u >> 16) & 1u)) >> 16);   // RNE
}
__device__ __forceinline__ float bf2f(unsigned short b) {
    return __uint_as_float(((unsigned)b) << 16);
}

// ---------------------------------------------------------------------------
// GRU step (h0=0), regenerate GCN weights, fold Wout/bout, transpose W2,
// and init the fixed-capacity bucket cursors (bfill[b] = b*BCAP).
// ---------------------------------------------------------------------------
__global__ void prep_k(const float* __restrict__ m1, const float* __restrict__ Wih1,
                       const float* __restrict__ bih1, const float* __restrict__ bhh1,
                       const float* __restrict__ m2, const float* __restrict__ Wih2,
                       const float* __restrict__ bih2, const float* __restrict__ bhh2,
                       const float* __restrict__ wtW1, const float* __restrict__ wtb1,
                       const float* __restrict__ wtW2, const float* __restrict__ wtb2,
                       const float* __restrict__ Wout, const float* __restrict__ bout,
                       const float* __restrict__ W2,
                       float* __restrict__ Wn1, float* __restrict__ Wn2,
                       float* __restrict__ wsum, float* __restrict__ bsum,
                       float* __restrict__ W2t, int* __restrict__ bfill, int NBK) {
    __shared__ float nm[32];   // new_mem1 [0..15], new_mem2 [16..31]
    int t = threadIdx.x;
    if (t < 32) {
        int L = t >> 4, j = t & 15;
        const float* m   = L ? m2   : m1;
        const float* Wih = L ? Wih2 : Wih1;
        const float* bih = L ? bih2 : bih1;
        const float* bhh = L ? bhh2 : bhh1;
        float gr = bih[j], gz = bih[16 + j], gn = bih[32 + j];
        for (int k = 0; k < 16; ++k) {
            float mk = m[k];
            gr += Wih[j * 16 + k] * mk;
            gz += Wih[(16 + j) * 16 + k] * mk;
            gn += Wih[(32 + j) * 16 + k] * mk;
        }
        float r = 1.f / (1.f + expf(-(gr + bhh[j])));
        float z = 1.f / (1.f + expf(-(gz + bhh[16 + j])));
        float n = tanhf(gn + r * bhh[32 + j]);
        nm[t] = (1.f - z) * n;          // + z*h, h==0
    }
    __syncthreads();
    float s1 = wtb1[t], s2 = wtb2[t];
    for (int k = 0; k < 16; ++k) {
        s1 += wtW1[t * 16 + k] * nm[k];
        s2 += wtW2[t * 16 + k] * nm[16 + k];
    }
    Wn1[t] = s1;
    Wn2[t] = s2;
#pragma unroll
    for (int j = 0; j < 16; ++j) W2t[t * 16 + j] = W2[j * 256 + t];
    if (t < 16) wsum[t] = Wout[t] + Wout[16 + t];
    if (t == 0) bsum[0] = bout[0] + bout[1];
    for (int i = t; i < NBK; i += 256) bfill[i] = i * BCAP;
}

// Split W1 into bf16 hi/lo pair (for split-bf16 MFMA GEMM). 32768 elems.
__global__ void wsplit_k(const float* __restrict__ W1,
                         unsigned short* __restrict__ W1h,
                         unsigned short* __restrict__ W1l) {
    int i = blockIdx.x * 256 + threadIdx.x;
    float v = W1[i];
    unsigned short h = f2bf(v);
    W1h[i] = h;
    W1l[i] = f2bf(v - bf2f(h));
}

// ---------------------------------------------------------------------------
// CSR build: bscat (fixed-base buckets) -> cscan (1 block) -> bproc.
// ---------------------------------------------------------------------------
__global__ void bscat_k(const int* __restrict__ row, const int* __restrict__ col,
                        int* __restrict__ bfill, int2* __restrict__ stage,
                        int E, int NBK) {
    __shared__ int lcnt[NBKMAX];
    __shared__ int lbase[NBKMAX];
    int t = threadIdx.x;
    for (int i = t; i < NBK; i += 256) lcnt[i] = 0;
    __syncthreads();
    int base = blockIdx.x * 4096;
    int r[16], d[16], sl[16];
#pragma unroll
    for (int i = 0; i < 16; ++i) {
        int e = base + i * 256 + t;
        if (e < E) {
            r[i]  = row[e];
            d[i]  = col[e];
            sl[i] = atomicAdd(&lcnt[d[i] >> BSH2], 1);
        } else d[i] = -1;
    }
    __syncthreads();
    for (int i = t; i < NBK; i += 256)
        lbase[i] = lcnt[i] ? atomicAdd(bfill + i, lcnt[i]) : 0;
    __syncthreads();
#pragma unroll
    for (int i = 0; i < 16; ++i) {
        if (d[i] >= 0)
            stage[lbase[d[i] >> BSH2] + sl[i]] = make_int2(r[i], d[i]);
    }
}

// single block: counts from bfill, exclusive scan -> contiguous CSR bases
__global__ __launch_bounds__(512) void cscan_k(const int* __restrict__ bfill,
                                               int* __restrict__ bbase2,
                                               int* __restrict__ off,
                                               int NBK, int N, int E) {
    __shared__ int s[512];
    int t = threadIdx.x;
    int v = (t < NBK) ? (bfill[t] - t * BCAP) : 0;
    s[t] = v;
    __syncthreads();
    for (int d = 1; d < 512; d <<= 1) {
        int u = (t >= d) ? s[t - d] : 0;
        __syncthreads();
        s[t] += u;
        __syncthreads();
    }
    if (t < NBK) bbase2[t] = s[t] - v;
    if (t == 0) { bbase2[NBK] = E; off[N] = E; }
}

// one block per 256-dest bucket: LDS hist (1 counter/thread) -> 256-scan ->
// off/dis -> in-window scatter (~32 KB window, L2-resident). LDS atomics only.
__global__ void bproc_k(const int2* __restrict__ stage, const int* __restrict__ bbase2,
                        int* __restrict__ off, float* __restrict__ dis,
                        int* __restrict__ srcs, int N) {
    __shared__ int lh[BKS];    // counts, then cursors
    __shared__ int ssc[BKS];   // scan
    const int b  = blockIdx.x;
    const int t  = threadIdx.x;
    const int sb = b * BCAP;                     // stage read base
    const int e0 = bbase2[b];
    const int cnt = bbase2[b + 1] - e0;
    lh[t] = 0;
    __syncthreads();
    for (int i = t; i < cnt; i += 256) {
        int2 v = stage[sb + i];
        atomicAdd(&lh[v.y & (BKS - 1)], 1);
    }
    __syncthreads();
    int c = lh[t];
    ssc[t] = c;
    __syncthreads();
    for (int d = 1; d < 256; d <<= 1) {
        int u = (t >= d) ? ssc[t - d] : 0;
        __syncthreads();
        ssc[t] += u;
        __syncthreads();
    }
    int ex = ssc[t] - c;       // exclusive offset within bucket
    {
        int node = b * BKS + t;
        if (node < N) {
            off[node] = e0 + ex;
            dis[node] = rsqrtf((float)(c + 1));   // in-degree + self-loop
        }
    }
    __syncthreads();
    lh[t] = ex;                // cursors
    __syncthreads();
    for (int i = t; i < cnt; i += 256) {
        int2 w = stage[sb + i];
        int pos = e0 + atomicAdd(&lh[w.y & (BKS - 1)], 1);
        srcs[pos] = w.x;
    }
}

// ---------------------------------------------------------------------------
// Fused MLP v5 (split-bf16 MFMA, 8 waves / 512 threads per 64-node block).
// ---------------------------------------------------------------------------
__global__ __launch_bounds__(512, 4) void mlp_k(
        const float* __restrict__ x,
        const unsigned short* __restrict__ W1h,
        const unsigned short* __restrict__ W1l,
        const float* __restrict__ b1, const float* __restrict__ W2t,
        const float* __restrict__ b2, const float* __restrict__ Wn1,
        const float* __restrict__ dis, float* __restrict__ xl, int N) {
    __shared__ float sbuf[17536];                    // 70144 B
    unsigned short* xh  = (unsigned short*)sbuf;     // [64][136] bf16 hi
    unsigned short* xlo = (unsigned short*)sbuf + 8704;  // [64][136] bf16 lo
    float* h1s = sbuf;                               // [64][257] fp32 (overlay)
    float* h2s = sbuf + 16448;                       // [64][17]

    const int t      = threadIdx.x;
    const int nl     = t & 63;
    const int q      = __builtin_amdgcn_readfirstlane(t >> 6);  // wave 0..7
    const int lane15 = t & 15;
    const int quad   = (t & 63) >> 4;
    const int node   = blockIdx.x * 64 + nl;

    // ---- stage x: wave q stages k in [q*16, q*16+16) for its node ----
    {
        unsigned* xh32 = (unsigned*)xh;
        unsigned* xl32 = (unsigned*)xlo;
        int base = nl * 68 + q * 8;                  // uint index (row stride 68)
        if (node < N) {
            const float4* xr = (const float4*)(x + (size_t)node * 128) + q * 4;
#pragma unroll
            for (int kk = 0; kk < 4; ++kk) {
                float4 v = xr[kk];
                unsigned short hx = f2bf(v.x), hy = f2bf(v.y);
                unsigned short hz = f2bf(v.z), hw = f2bf(v.w);
                unsigned short lx = f2bf(v.x - bf2f(hx)), ly = f2bf(v.y - bf2f(hy));
                unsigned short lz = f2bf(v.z - bf2f(hz)), lw = f2bf(v.w - bf2f(hw));
                xh32[base + kk * 2]     = (unsigned)hx | ((unsigned)hy << 16);
                xh32[base + kk * 2 + 1] = (unsigned)hz | ((unsigned)hw << 16);
                xl32[base + kk * 2]     = (unsigned)lx | ((unsigned)ly << 16);
                xl32[base + kk * 2 + 1] = (unsigned)lz | ((unsigned)lw << 16);
            }
        } else {
#pragma unroll
            for (int kk = 0; kk < 4; ++kk) {
                xh32[base + kk * 2] = 0u; xh32[base + kk * 2 + 1] = 0u;
                xl32[base + kk * 2] = 0u; xl32[base + kk * 2 + 1] = 0u;
            }
        }
    }
    __syncthreads();

    // ---- GEMM1: wave q owns hu in [q*32, q*32+32); 4 m-tiles x 2 n-tiles ----
    f32x4 acc[4][2];
#pragma unroll
    for (int mt = 0; mt < 4; ++mt)
#pragma unroll
        for (int nt = 0; nt < 2; ++nt)
            acc[mt][nt] = (f32x4){0.f, 0.f, 0.f, 0.f};

#pragma unroll 1
    for (int ks = 0; ks < 4; ++ks) {
        bf16x8 ah[4], al[4];
        const int koff = ks * 32 + quad * 8;
#pragma unroll
        for (int mt = 0; mt < 4; ++mt) {
            ah[mt] = *(const bf16x8*)(xh  + (16 * mt + lane15) * 136 + koff);
            al[mt] = *(const bf16x8*)(xlo + (16 * mt + lane15) * 136 + koff);
        }
#pragma unroll
        for (int nt = 0; nt < 2; ++nt) {
            size_t wo = (size_t)(q * 32 + nt * 16 + lane15) * 128 + koff;
            bf16x8 bh = *(const bf16x8*)(W1h + wo);
            bf16x8 bl = *(const bf16x8*)(W1l + wo);
#pragma unroll
            for (int mt = 0; mt < 4; ++mt) {
                acc[mt][nt] = __builtin_amdgcn_mfma_f32_16x16x32_bf16(ah[mt], bh, acc[mt][nt], 0, 0, 0);
                acc[mt][nt] = __builtin_amdgcn_mfma_f32_16x16x32_bf16(ah[mt], bl, acc[mt][nt], 0, 0, 0);
                acc[mt][nt] = __builtin_amdgcn_mfma_f32_16x16x32_bf16(al[mt], bh, acc[mt][nt], 0, 0, 0);
            }
        }
    }
    __syncthreads();   // x tile dead; safe to overlay h1s

    // ---- epilogue GEMM1: h1s[row][hu] = lrelu(acc + b1[hu]) ----
#pragma unroll
    for (int nt = 0; nt < 2; ++nt) {
        int hu = q * 32 + nt * 16 + lane15;
        float bb = b1[hu];
#pragma unroll
        for (int mt = 0; mt < 4; ++mt) {
            int rbase = (16 * mt + quad * 4) * 257 + hu;
#pragma unroll
            for (int r = 0; r < 4; ++r)
                h1s[rbase + r * 257] = lrelu(acc[mt][nt][r] + bb);
        }
    }
    __syncthreads();

    // ---- stage2: wave q computes j in {2q, 2q+1} for its node nl ----
    {
        float a2[2] = {0.f, 0.f};
        const float* h1r = h1s + nl * 257;
        for (int hu = 0; hu < 256; hu += 4) {
#pragma unroll
            for (int u = 0; u < 4; ++u) {
                float h = h1r[hu + u];
                const float* wr = W2t + (hu + u) * 16 + q * 2;   // uniform -> s_load
                a2[0] = fmaf(h, wr[0], a2[0]);
                a2[1] = fmaf(h, wr[1], a2[1]);
            }
        }
#pragma unroll
        for (int jj = 0; jj < 2; ++jj) {
            int j = q * 2 + jj;
            h2s[nl * 17 + j] = lrelu(a2[jj] + b2[j]);
        }
    }
    __syncthreads();

    // ---- stage3 (waves 0..3): o = h2 @ Wn1^T, scaled by dis ----
    if (q < 4) {
        const int c0 = q * 4;
        float o[4];
#pragma unroll
        for (int cc = 0; cc < 4; ++cc) {
            float s = 0.f;
#pragma unroll
            for (int j = 0; j < 16; ++j)
                s = fmaf(Wn1[(c0 + cc) * 16 + j], h2s[nl * 17 + j], s);
            o[cc] = s;
        }
        if (node < N) {
            float d = dis[node];
            float4* xo = (float4*)(xl + (size_t)node * 16 + c0);
            *xo = make_float4(d * o[0], d * o[1], d * o[2], d * o[3]);
        }
    }
}

// ---------------------------------------------------------------------------
// Gather layer 1 (wave per node, 4-deep batched gathers — R11-proven)
// ---------------------------------------------------------------------------
__global__ void gather1_k(const int* __restrict__ off, const int* __restrict__ srcs,
                          const float* __restrict__ dis, const float* __restrict__ xin,
                          const float* __restrict__ bias, const float* __restrict__ Wn2,
                          float* __restrict__ xout, int N) {
    __shared__ float w[256];             // transposed: w[j*16+c] = Wn2[c*16+j]
    {
        int j = threadIdx.x >> 4, c = threadIdx.x & 15;
        w[threadIdx.x] = Wn2[c * 16 + j];
    }
    __syncthreads();
    int t = blockIdx.x * 256 + threadIdx.x;
    int n = t >> 6;
    if (n >= N) return;
    int lane = t & 63, sub = lane >> 4, c = lane & 15;
    float acc = (sub == 0) ? xin[(size_t)n * 16 + c] : 0.f;   // self term
    int e  = off[n] + sub;
    int e1 = off[n + 1];
    for (; e + 12 < e1; e += 16) {
        int s0 = srcs[e], s1 = srcs[e + 4], s2 = srcs[e + 8], s3 = srcs[e + 12];
        float v0 = xin[(size_t)s0 * 16 + c];
        float v1 = xin[(size_t)s1 * 16 + c];
        float v2 = xin[(size_t)s2 * 16 + c];
        float v3 = xin[(size_t)s3 * 16 + c];
        acc += (v0 + v1) + (v2 + v3);
    }
    for (; e < e1; e += 4)
        acc += xin[(size_t)srcs[e] * 16 + c];
    acc += __shfl_xor(acc, 16);
    acc += __shfl_xor(acc, 32);
    float d = dis[n];
    float h = lrelu(fmaf(d, acc, bias[c]));
    float o = 0.f;
#pragma unroll
    for (int j = 0; j < 16; ++j) o = fmaf(w[j * 16 + c], __shfl(h, j, 16), o);
    if (sub == 0) xout[(size_t)n * 16 + c] = d * o;
}

// ---------------------------------------------------------------------------
// Gather layer 2 + final projection (same 4-deep batching)
// ---------------------------------------------------------------------------
__global__ void gather2_k(const int* __restrict__ off, const int* __restrict__ srcs,
                          const float* __restrict__ dis, const float* __restrict__ xin,
                          const float* __restrict__ bias, const float* __restrict__ wsum,
                          const float* __restrict__ bsum, float* __restrict__ out, int N) {
    int t = blockIdx.x * 256 + threadIdx.x;
    int n = t >> 6;
    if (n >= N) return;
    int lane = t & 63, sub = lane >> 4, c = lane & 15;
    float acc = (sub == 0) ? xin[(size_t)n * 16 + c] : 0.f;
    int e  = off[n] + sub;
    int e1 = off[n + 1];
    for (; e + 12 < e1; e += 16) {
        int s0 = srcs[e], s1 = srcs[e + 4], s2 = srcs[e + 8], s3 = srcs[e + 12];
        float v0 = xin[(size_t)s0 * 16 + c];
        float v1 = xin[(size_t)s1 * 16 + c];
        float v2 = xin[(size_t)s2 * 16 + c];
        float v3 = xin[(size_t)s3 * 16 + c];
        acc += (v0 + v1) + (v2 + v3);
    }
    for (; e < e1; e += 4)
        acc += xin[(size_t)srcs[e] * 16 + c];
    acc += __shfl_xor(acc, 16);
    acc += __shfl_xor(acc, 32);
    float v = wsum[c] * lrelu(fmaf(dis[n], acc, bias[c]));
#pragma unroll
    for (int m = 1; m < 16; m <<= 1) v += __shfl_xor(v, m);
    if (lane == 0) out[n] = v + bsum[0];
}

// ---------------------------------------------------------------------------
extern "C" void kernel_launch(void* const* d_in, const int* in_sizes, int n_in,
                              void* d_out, int out_size, void* d_ws, size_t ws_size,
                              hipStream_t stream) {
    const float* x      = (const float*)d_in[0];
    const int*   edge   = (const int*)d_in[1];
    const float* W1     = (const float*)d_in[2];
    const float* b1     = (const float*)d_in[3];
    const float* W2     = (const float*)d_in[4];
    const float* b2     = (const float*)d_in[5];
    const float* mem1   = (const float*)d_in[6];
    const float* g1_Wih = (const float*)d_in[7];
    const float* g1_bih = (const float*)d_in[9];
    const float* g1_bhh = (const float*)d_in[10];
    const float* wt1_W  = (const float*)d_in[11];
    const float* wt1_b  = (const float*)d_in[12];
    const float* gcn1_b = (const float*)d_in[13];
    const float* mem2   = (const float*)d_in[14];
    const float* g2_Wih = (const float*)d_in[15];
    const float* g2_bih = (const float*)d_in[17];
    const float* g2_bhh = (const float*)d_in[18];
    const float* wt2_W  = (const float*)d_in[19];
    const float* wt2_b  = (const float*)d_in[20];
    const float* gcn2_b = (const float*)d_in[21];
    const float* Wout   = (const float*)d_in[22];
    const float* bout   = (const float*)d_in[23];
    float* out = (float*)d_out;

    const int N = in_sizes[0] / 128;
    const int E = in_sizes[1] / 2;
    const int* row = edge;
    const int* col = edge + E;

    const int NBK = (N + BKS - 1) >> BSH2;   // coarse buckets (391 @ N=100k)
    const int gM  = (N + 63) / 64;           // mlp blocks (64 nodes, 512 thr)
    const int gG  = (N * 64 + 255) / 256;    // gather blocks (wave per node)
    const int gB  = (E + 4095) / 4096;       // bscat blocks

    float* ws    = (float*)d_ws;
    float* bufA  = ws;                        // [N*16] xl1 (dis-scaled)
    float* bufB  = bufA + (size_t)N * 16;     // [N*16] xl2 (dis-scaled)
    float* dis   = bufB + (size_t)N * 16;     // [N]
    float* sm    = dis + N;                   // smalls
    float* Wn1   = sm;
    float* Wn2   = sm + 256;
    float* wsum  = sm + 512;
    float* bsum  = sm + 528;
    float* W2t   = sm + 544;                  // [256*16] transposed W2
    unsigned short* W1h = (unsigned short*)(sm + 4640);   // [256*128] bf16 hi
    unsigned short* W1l = (unsigned short*)(sm + 21024);  // [256*128] bf16 lo
    int*   bfill = (int*)(sm + 37408);        // [NBKMAX]
    int*   bbase2= bfill + NBKMAX;            // [NBKMAX+1]
    int*   off   = bbase2 + NBKMAX + 1;       // [N+1]
    int*   srcs  = off + N + 1;               // [E]
    // stage: 16B-aligned int2[NBK*BCAP]
    size_t stoff = (size_t)(srcs + E - (int*)d_ws);
    stoff = (stoff + 3) & ~(size_t)3;
    int2*  stage = (int2*)((int*)d_ws + stoff);

    prep_k<<<1, 256, 0, stream>>>(mem1, g1_Wih, g1_bih, g1_bhh,
                                  mem2, g2_Wih, g2_bih, g2_bhh,
                                  wt1_W, wt1_b, wt2_W, wt2_b,
                                  Wout, bout, W2, Wn1, Wn2, wsum, bsum,
                                  W2t, bfill, NBK);
    wsplit_k<<<128, 256, 0, stream>>>(W1, W1h, W1l);
    bscat_k<<<gB, 256, 0, stream>>>(row, col, bfill, stage, E, NBK);
    cscan_k<<<1, 512, 0, stream>>>(bfill, bbase2, off, NBK, N, E);
    bproc_k<<<NBK, 256, 0, stream>>>(stage, bbase2, off, dis, srcs, N);
    mlp_k<<<gM, 512, 0, stream>>>(x, W1h, W1l, b1, W2t, b2, Wn1, dis, bufA, N);
    gather1_k<<<gG, 256, 0, stream>>>(off, srcs, dis, bufA, gcn1_b, Wn2, bufB, N);
    gather2_k<<<gG, 256, 0, stream>>>(off, srcs, dis, bufB, gcn2_b, wsum, bsum, out, N);
}